// Round 2
// baseline (419.235 us; speedup 1.0000x reference)
//
#include <hip/hip_runtime.h>

// Problem constants (match reference)
#define T_TICKS 128
#define NCHAN   1536
#define NCPAIR  10000
#define NCROSS  30000
#define E_EDGES 120000

// ---------------- CSR build (graph is tick-independent) ----------------

__global__ void k_hist(const int* __restrict__ dst, int* __restrict__ counts) {
    int i = blockIdx.x * blockDim.x + threadIdx.x;
    if (i < E_EDGES) atomicAdd(&counts[dst[i]], 1);
}

// single block, 1024 threads: exclusive scan of 30000 counts -> indptr[30001], cursor copy
__global__ void k_scan(const int* __restrict__ counts, int* __restrict__ indptr,
                       int* __restrict__ cursor) {
    __shared__ int sums[1024];
    const int tid = threadIdx.x;
    const int per = (NCROSS + 1023) / 1024;  // 30
    const int base = tid * per;
    int local = 0;
    for (int k = 0; k < per; k++) {
        int idx = base + k;
        if (idx < NCROSS) local += counts[idx];
    }
    sums[tid] = local;
    __syncthreads();
    // Hillis-Steele inclusive scan over 1024 partials
    for (int off = 1; off < 1024; off <<= 1) {
        int v = (tid >= off) ? sums[tid - off] : 0;
        __syncthreads();
        sums[tid] += v;
        __syncthreads();
    }
    int run = (tid == 0) ? 0 : sums[tid - 1];  // exclusive prefix
    for (int k = 0; k < per; k++) {
        int idx = base + k;
        if (idx < NCROSS) {
            indptr[idx] = run;
            cursor[idx] = run;
            run += counts[idx];
        }
    }
    if (tid == 1023) indptr[NCROSS] = sums[1023];
}

__global__ void k_scatter(const int* __restrict__ src, const int* __restrict__ dst,
                          int* __restrict__ cursor, int* __restrict__ sorted_src) {
    int i = blockIdx.x * blockDim.x + threadIdx.x;
    if (i < E_EDGES) {
        int p = atomicAdd(&cursor[dst[i]], 1);
        sorted_src[p] = src[i];
    }
}

// ---------------- node features -> h = nodes @ W_gat + b ----------------

__global__ void k_h(const float* __restrict__ x,
                    const int* __restrict__ c0, const int* __restrict__ c1,
                    const int* __restrict__ c2,
                    const int* __restrict__ g01, const int* __restrict__ g12,
                    const int* __restrict__ g20,
                    const float* __restrict__ r01,
                    const float* __restrict__ r12,
                    const float* __restrict__ r20,
                    const float* __restrict__ Wg,
                    const float* __restrict__ bg,
                    float* __restrict__ h) {
    const int n = blockIdx.x * blockDim.x + threadIdx.x;
    const int t = blockIdx.y;
    if (n >= NCROSS) return;

    int iA, iB, m;
    float pA, pB;
    const int* cA;
    const int* cB;
    const float* ray;
    if (n < NCPAIR) {
        m = n; cA = c0; cB = c1; pA = 0.f; pB = 1.f; ray = r01;
        iA = g01[2 * m]; iB = g01[2 * m + 1];
    } else if (n < 2 * NCPAIR) {
        m = n - NCPAIR; cA = c1; cB = c2; pA = 1.f; pB = 2.f; ray = r12;
        iA = g12[2 * m]; iB = g12[2 * m + 1];
    } else {
        m = n - 2 * NCPAIR; cA = c2; cB = c0; pA = 2.f; pB = 0.f; ray = r20;
        iA = g20[2 * m]; iB = g20[2 * m + 1];
    }
    const int chA = cA[iA];
    const int chB = cB[iB];
    const float sigA = x[chA * T_TICKS + t];  // x: [1,1,NCHAN,T]
    const float sigB = x[chB * T_TICKS + t];
    const float rx = ray[2 * m];
    const float ry = ray[2 * m + 1];

    // feats: [sigA, wA, chA, 0, pA, sigB, wB, chB, 0, pB, rx, ry, tick]
    float f[13] = {sigA, (float)iA, (float)chA, 0.f, pA,
                   sigB, (float)iB, (float)chB, 0.f, pB,
                   rx,   ry,        (float)t};
    float hv[4];
#pragma unroll
    for (int c = 0; c < 4; c++) hv[c] = bg[c];
#pragma unroll
    for (int k = 0; k < 13; k++) {
        const float fk = f[k];
#pragma unroll
        for (int c = 0; c < 4; c++) hv[c] += fk * Wg[k * 4 + c];
    }
    float4* hp = (float4*)h;
    hp[(size_t)t * NCROSS + n] = make_float4(hv[0], hv[1], hv[2], hv[3]);
}

// ---------------- GAT aggregation + MLP + sigmoid ----------------

__global__ void k_gat(const float* __restrict__ h, const int* __restrict__ indptr,
                      const int* __restrict__ ssrc,
                      const float* __restrict__ as_,
                      const float* __restrict__ ad_,
                      const float* __restrict__ Wm,
                      const float* __restrict__ bm,
                      float* __restrict__ out) {
    const int n = blockIdx.x * blockDim.x + threadIdx.x;
    const int t = blockIdx.y;
    if (n >= NCROSS) return;

    const float4* hp = (const float4*)h + (size_t)t * NCROSS;
    const float a0 = as_[0], a1 = as_[1], a2 = as_[2], a3 = as_[3];
    const float d0 = ad_[0], d1 = ad_[1], d2 = ad_[2], d3 = ad_[3];

    const float4 hd = hp[n];
    const float dd = hd.x * d0 + hd.y * d1 + hd.z * d2 + hd.w * d3;

    const int beg = indptr[n];
    const int end = indptr[n + 1];

    float mmax = -INFINITY;
    for (int j = beg; j < end; j++) {
        const float4 hs = hp[ssrc[j]];
        float e = hs.x * a0 + hs.y * a1 + hs.z * a2 + hs.w * a3 + dd;
        e = (e > 0.f) ? e : 0.2f * e;
        mmax = fmaxf(mmax, e);
    }
    float denom = 0.f, m0 = 0.f, m1 = 0.f, m2 = 0.f, m3 = 0.f;
    for (int j = beg; j < end; j++) {
        const float4 hs = hp[ssrc[j]];
        float e = hs.x * a0 + hs.y * a1 + hs.z * a2 + hs.w * a3 + dd;
        e = (e > 0.f) ? e : 0.2f * e;
        const float w = __expf(e - mmax);
        denom += w;
        m0 += w * hs.x; m1 += w * hs.y; m2 += w * hs.z; m3 += w * hs.w;
    }
    const float inv = 1.f / (denom + 1e-9f);
    const float g0 = m0 * inv, g1 = m1 * inv, g2 = m2 * inv, g3 = m3 * inv;
    const float logit = g0 * Wm[0] + g1 * Wm[1] + g2 * Wm[2] + g3 * Wm[3] + bm[0];
    const float o = 1.f / (1.f + __expf(-logit));
    out[(size_t)t * NCROSS + n] = o;
}

// ---------------- launch ----------------

extern "C" void kernel_launch(void* const* d_in, const int* in_sizes, int n_in,
                              void* d_out, int out_size, void* d_ws, size_t ws_size,
                              hipStream_t stream) {
    const float* x   = (const float*)d_in[0];
    const int* c0  = (const int*)d_in[1];
    const int* c1  = (const int*)d_in[2];
    const int* c2  = (const int*)d_in[3];
    const int* g01 = (const int*)d_in[4];
    const int* g12 = (const int*)d_in[5];
    const int* g20 = (const int*)d_in[6];
    const float* r01 = (const float*)d_in[7];
    const float* r12 = (const float*)d_in[8];
    const float* r20 = (const float*)d_in[9];
    const int* edges = (const int*)d_in[10];          // [2, E]
    const float* Wg  = (const float*)d_in[11];
    const float* as_ = (const float*)d_in[12];
    const float* ad_ = (const float*)d_in[13];
    const float* bg  = (const float*)d_in[14];
    const float* Wm  = (const float*)d_in[15];
    const float* bm  = (const float*)d_in[16];
    float* out = (float*)d_out;

    const int* e_src = edges;
    const int* e_dst = edges + E_EDGES;

    // workspace layout: small CSR arrays first, big h slab after
    char* ws = (char*)d_ws;
    size_t off = 0;
    int* counts       = (int*)(ws + off); off += NCROSS * sizeof(int);
    int* indptr       = (int*)(ws + off); off += (NCROSS + 1) * sizeof(int);
    int* cursor       = (int*)(ws + off); off += NCROSS * sizeof(int);
    int* sorted_src   = (int*)(ws + off); off += E_EDGES * sizeof(int);
    off = (off + 255) & ~(size_t)255;
    float* h          = (float*)(ws + off);  // 61,440,000 B
    (void)ws_size; (void)n_in; (void)in_sizes; (void)out_size;

    hipMemsetAsync(counts, 0, NCROSS * sizeof(int), stream);

    const int eb = (E_EDGES + 255) / 256;
    k_hist<<<eb, 256, 0, stream>>>(e_dst, counts);
    k_scan<<<1, 1024, 0, stream>>>(counts, indptr, cursor);
    k_scatter<<<eb, 256, 0, stream>>>(e_src, e_dst, cursor, sorted_src);

    dim3 gridN((NCROSS + 255) / 256, T_TICKS);
    k_h<<<gridN, 256, 0, stream>>>(x, c0, c1, c2, g01, g12, g20, r01, r12, r20,
                                   Wg, bg, h);
    k_gat<<<gridN, 256, 0, stream>>>(h, indptr, sorted_src, as_, ad_, Wm, bm, out);
}

// Round 3
// 285.176 us; speedup vs baseline: 1.4701x; 1.4701x over previous
//
#include <hip/hip_runtime.h>

// Problem constants (match reference)
#define T_TICKS 128
#define NCHAN   1536
#define NCPAIR  10000
#define NCROSS  30000
#define E_EDGES 120000
#define TG      8              // ticks per group
#define NTG     (T_TICKS / TG) // 16 tick groups
#define NBLK_N  ((NCROSS + 255) / 256)  // 118 blocks over nodes

// ---------------- CSR build (graph is tick-independent) ----------------

__global__ void k_hist(const int* __restrict__ dst, int* __restrict__ counts) {
    int i = blockIdx.x * blockDim.x + threadIdx.x;
    if (i < E_EDGES) atomicAdd(&counts[dst[i]], 1);
}

// single block, 1024 threads: exclusive scan of 30000 counts -> indptr[30001], cursor copy
__global__ void k_scan(const int* __restrict__ counts, int* __restrict__ indptr,
                       int* __restrict__ cursor) {
    __shared__ int sums[1024];
    const int tid = threadIdx.x;
    const int per = (NCROSS + 1023) / 1024;  // 30
    const int base = tid * per;
    int local = 0;
    for (int k = 0; k < per; k++) {
        int idx = base + k;
        if (idx < NCROSS) local += counts[idx];
    }
    sums[tid] = local;
    __syncthreads();
    for (int off = 1; off < 1024; off <<= 1) {
        int v = (tid >= off) ? sums[tid - off] : 0;
        __syncthreads();
        sums[tid] += v;
        __syncthreads();
    }
    int run = (tid == 0) ? 0 : sums[tid - 1];  // exclusive prefix
    for (int k = 0; k < per; k++) {
        int idx = base + k;
        if (idx < NCROSS) {
            indptr[idx] = run;
            cursor[idx] = run;
            run += counts[idx];
        }
    }
    if (tid == 1023) indptr[NCROSS] = sums[1023];
}

__global__ void k_scatter(const int* __restrict__ src, const int* __restrict__ dst,
                          int* __restrict__ cursor, int* __restrict__ sorted_src) {
    int i = blockIdx.x * blockDim.x + threadIdx.x;
    if (i < E_EDGES) {
        int p = atomicAdd(&cursor[dst[i]], 1);
        sorted_src[p] = src[i];
    }
}

// ---------------- node features -> h = nodes @ W_gat + b ----------------
// h layout: [tg][n][8 ticks x 4 ch] = 128 B record per (node, tick-group)

__global__ void k_h(const float* __restrict__ x,
                    const int* __restrict__ c0, const int* __restrict__ c1,
                    const int* __restrict__ c2,
                    const int* __restrict__ g01, const int* __restrict__ g12,
                    const int* __restrict__ g20,
                    const float* __restrict__ r01,
                    const float* __restrict__ r12,
                    const float* __restrict__ r20,
                    const float* __restrict__ Wg,
                    const float* __restrict__ bg,
                    float* __restrict__ h) {
    const int n  = blockIdx.x * blockDim.x + threadIdx.x;
    const int tg = blockIdx.y;
    if (n >= NCROSS) return;

    int iA, iB, m;
    float pA, pB;
    const int* cA;
    const int* cB;
    const float* ray;
    if (n < NCPAIR) {
        m = n; cA = c0; cB = c1; pA = 0.f; pB = 1.f; ray = r01;
        iA = g01[2 * m]; iB = g01[2 * m + 1];
    } else if (n < 2 * NCPAIR) {
        m = n - NCPAIR; cA = c1; cB = c2; pA = 1.f; pB = 2.f; ray = r12;
        iA = g12[2 * m]; iB = g12[2 * m + 1];
    } else {
        m = n - 2 * NCPAIR; cA = c2; cB = c0; pA = 2.f; pB = 0.f; ray = r20;
        iA = g20[2 * m]; iB = g20[2 * m + 1];
    }
    const int chA = cA[iA];
    const int chB = cB[iB];
    const float rx = ray[2 * m];
    const float ry = ray[2 * m + 1];

    // tick-static part of nodes @ W_gat + b
    float base[4];
#pragma unroll
    for (int c = 0; c < 4; c++) {
        base[c] = bg[c]
                + (float)iA  * Wg[1 * 4 + c] + (float)chA * Wg[2 * 4 + c]
                + pA         * Wg[4 * 4 + c]
                + (float)iB  * Wg[6 * 4 + c] + (float)chB * Wg[7 * 4 + c]
                + pB         * Wg[9 * 4 + c]
                + rx         * Wg[10 * 4 + c] + ry * Wg[11 * 4 + c];
    }

    const float4 xa0 = *(const float4*)(x + chA * T_TICKS + tg * TG);
    const float4 xa1 = *(const float4*)(x + chA * T_TICKS + tg * TG + 4);
    const float4 xb0 = *(const float4*)(x + chB * T_TICKS + tg * TG);
    const float4 xb1 = *(const float4*)(x + chB * T_TICKS + tg * TG + 4);
    const float sa[8] = {xa0.x, xa0.y, xa0.z, xa0.w, xa1.x, xa1.y, xa1.z, xa1.w};
    const float sb[8] = {xb0.x, xb0.y, xb0.z, xb0.w, xb1.x, xb1.y, xb1.z, xb1.w};

    float4* rec = (float4*)(h + ((size_t)tg * NCROSS + n) * 32);
#pragma unroll
    for (int k = 0; k < TG; k++) {
        const float tk = (float)(tg * TG + k);
        float4 hv;
        hv.x = base[0] + sa[k] * Wg[0] + sb[k] * Wg[5 * 4 + 0] + tk * Wg[12 * 4 + 0];
        hv.y = base[1] + sa[k] * Wg[1] + sb[k] * Wg[5 * 4 + 1] + tk * Wg[12 * 4 + 1];
        hv.z = base[2] + sa[k] * Wg[2] + sb[k] * Wg[5 * 4 + 2] + tk * Wg[12 * 4 + 2];
        hv.w = base[3] + sa[k] * Wg[3] + sb[k] * Wg[5 * 4 + 3] + tk * Wg[12 * 4 + 3];
        rec[k] = hv;
    }
}

// ---------------- GAT aggregation + MLP + sigmoid ----------------
// one thread = (node, tick-group of 8); single-pass online softmax.

__global__ void k_gat(const float* __restrict__ h, const int* __restrict__ indptr,
                      const int* __restrict__ ssrc,
                      const float* __restrict__ as_,
                      const float* __restrict__ ad_,
                      const float* __restrict__ Wm,
                      const float* __restrict__ bm,
                      float* __restrict__ out) {
    // XCD-confined swizzle: linear block id -> (tg, node-block) such that
    // tick-group tg runs (heuristically) on XCD tg%8 -> per-XCD L2 holds one
    // 3.84 MB tg-slab of h.
    const int lid = blockIdx.x;
    const int xcd = lid & 7;
    const int s   = lid >> 3;            // 0 .. 2*NBLK_N-1
    const int half = s / NBLK_N;         // 0 or 1
    const int tg  = xcd + 8 * half;
    const int nb  = s - NBLK_N * half;
    const int n   = nb * 256 + threadIdx.x;
    if (n >= NCROSS) return;

    const float a0 = as_[0], a1 = as_[1], a2 = as_[2], a3 = as_[3];
    const float d0 = ad_[0], d1 = ad_[1], d2 = ad_[2], d3 = ad_[3];

    const float4* slab = (const float4*)(h + (size_t)tg * NCROSS * 32);

    // dd per tick from own record
    float dd[TG];
    {
        const float4* own = slab + (size_t)n * 8;
#pragma unroll
        for (int k = 0; k < TG; k++) {
            const float4 v = own[k];
            dd[k] = v.x * d0 + v.y * d1 + v.z * d2 + v.w * d3;
        }
    }

    float mx[TG], den[TG];
    float m0[TG], m1[TG], m2[TG], m3[TG];
#pragma unroll
    for (int k = 0; k < TG; k++) {
        mx[k] = -INFINITY; den[k] = 0.f;
        m0[k] = 0.f; m1[k] = 0.f; m2[k] = 0.f; m3[k] = 0.f;
    }

    const int beg = indptr[n];
    const int end = indptr[n + 1];
    for (int j = beg; j < end; j++) {
        const int src = ssrc[j];
        const float4* rec = slab + (size_t)src * 8;
#pragma unroll
        for (int k = 0; k < TG; k++) {
            const float4 hs = rec[k];
            float e = fmaf(hs.x, a0, fmaf(hs.y, a1, fmaf(hs.z, a2,
                      fmaf(hs.w, a3, dd[k]))));
            e = (e > 0.f) ? e : 0.2f * e;
            const float mn = fmaxf(mx[k], e);
            const float scale = __expf(mx[k] - mn);
            const float w = __expf(e - mn);
            mx[k] = mn;
            den[k] = den[k] * scale + w;
            m0[k] = m0[k] * scale + w * hs.x;
            m1[k] = m1[k] * scale + w * hs.y;
            m2[k] = m2[k] * scale + w * hs.z;
            m3[k] = m3[k] * scale + w * hs.w;
        }
    }

    const float w0 = Wm[0], w1 = Wm[1], w2 = Wm[2], w3 = Wm[3], bb = bm[0];
#pragma unroll
    for (int k = 0; k < TG; k++) {
        const float inv = 1.f / (den[k] + 1e-9f);
        const float logit = (m0[k] * w0 + m1[k] * w1 + m2[k] * w2 + m3[k] * w3)
                            * inv + bb;
        const float o = 1.f / (1.f + __expf(-logit));
        out[(size_t)(tg * TG + k) * NCROSS + n] = o;
    }
}

// ---------------- launch ----------------

extern "C" void kernel_launch(void* const* d_in, const int* in_sizes, int n_in,
                              void* d_out, int out_size, void* d_ws, size_t ws_size,
                              hipStream_t stream) {
    const float* x   = (const float*)d_in[0];
    const int* c0  = (const int*)d_in[1];
    const int* c1  = (const int*)d_in[2];
    const int* c2  = (const int*)d_in[3];
    const int* g01 = (const int*)d_in[4];
    const int* g12 = (const int*)d_in[5];
    const int* g20 = (const int*)d_in[6];
    const float* r01 = (const float*)d_in[7];
    const float* r12 = (const float*)d_in[8];
    const float* r20 = (const float*)d_in[9];
    const int* edges = (const int*)d_in[10];          // [2, E]
    const float* Wg  = (const float*)d_in[11];
    const float* as_ = (const float*)d_in[12];
    const float* ad_ = (const float*)d_in[13];
    const float* bg  = (const float*)d_in[14];
    const float* Wm  = (const float*)d_in[15];
    const float* bm  = (const float*)d_in[16];
    float* out = (float*)d_out;

    const int* e_src = edges;
    const int* e_dst = edges + E_EDGES;

    // workspace layout: small CSR arrays first, big h slab after
    char* ws = (char*)d_ws;
    size_t off = 0;
    int* counts       = (int*)(ws + off); off += NCROSS * sizeof(int);
    int* indptr       = (int*)(ws + off); off += (NCROSS + 1) * sizeof(int);
    int* cursor       = (int*)(ws + off); off += NCROSS * sizeof(int);
    int* sorted_src   = (int*)(ws + off); off += E_EDGES * sizeof(int);
    off = (off + 255) & ~(size_t)255;
    float* h          = (float*)(ws + off);  // 61,440,000 B
    (void)ws_size; (void)n_in; (void)in_sizes; (void)out_size;

    hipMemsetAsync(counts, 0, NCROSS * sizeof(int), stream);

    const int eb = (E_EDGES + 255) / 256;
    k_hist<<<eb, 256, 0, stream>>>(e_dst, counts);
    k_scan<<<1, 1024, 0, stream>>>(counts, indptr, cursor);
    k_scatter<<<eb, 256, 0, stream>>>(e_src, e_dst, cursor, sorted_src);

    dim3 gridH(NBLK_N, NTG);
    k_h<<<gridH, 256, 0, stream>>>(x, c0, c1, c2, g01, g12, g20, r01, r12, r20,
                                   Wg, bg, h);
    k_gat<<<NBLK_N * NTG, 256, 0, stream>>>(h, indptr, sorted_src, as_, ad_,
                                            Wm, bm, out);
}

// Round 4
// 209.861 us; speedup vs baseline: 1.9977x; 1.3589x over previous
//
#include <hip/hip_runtime.h>

// Problem constants (match reference)
#define T_TICKS 128
#define NCHAN   1536
#define NCPAIR  10000
#define NCROSS  30000
#define E_EDGES 120000
#define TG      8              // ticks per group
#define NTG     (T_TICKS / TG) // 16 tick groups
#define NBLK_N  ((NCROSS + 255) / 256)  // 118 blocks over nodes
#define DEGBINS 64

// ---------------- CSR build (graph is tick-independent) ----------------

__global__ void k_hist(const int* __restrict__ dst, int* __restrict__ counts) {
    int i = blockIdx.x * blockDim.x + threadIdx.x;
    if (i < E_EDGES) atomicAdd(&counts[dst[i]], 1);
}

// 118 blocks x 256: per-block sum of counts + degree histogram (LDS-aggregated)
__global__ void k_pre(const int* __restrict__ counts, int* __restrict__ blocksum,
                      int* __restrict__ degbins) {
    __shared__ int wsum[4];
    __shared__ int lbins[DEGBINS];
    const int tid = threadIdx.x;
    const int n = blockIdx.x * 256 + tid;
    if (tid < DEGBINS) lbins[tid] = 0;
    __syncthreads();
    int c = (n < NCROSS) ? counts[n] : 0;
    if (n < NCROSS) {
        int b = c < DEGBINS ? c : DEGBINS - 1;
        atomicAdd(&lbins[b], 1);
    }
    // wave reduce
    int v = c;
    for (int o = 32; o > 0; o >>= 1) v += __shfl_down(v, o, 64);
    if ((tid & 63) == 0) wsum[tid >> 6] = v;
    __syncthreads();
    if (tid == 0) blocksum[blockIdx.x] = wsum[0] + wsum[1] + wsum[2] + wsum[3];
    if (tid < DEGBINS && lbins[tid] > 0) atomicAdd(&degbins[tid], lbins[tid]);
}

// 1 block, 128 threads: scan blocksum[118] -> blockoff; descending-degree
// exclusive offsets -> degcur
__global__ void k_top(const int* __restrict__ blocksum, int* __restrict__ blockoff,
                      const int* __restrict__ degbins, int* __restrict__ degcur) {
    __shared__ int s[128];
    __shared__ int lb[DEGBINS];
    __shared__ int lo[DEGBINS];
    const int tid = threadIdx.x;
    int orig = (tid < NBLK_N) ? blocksum[tid] : 0;
    s[tid] = orig;
    if (tid < DEGBINS) lb[tid] = degbins[tid];
    __syncthreads();
    for (int off = 1; off < 128; off <<= 1) {
        int v = (tid >= off) ? s[tid - off] : 0;
        __syncthreads();
        s[tid] += v;
        __syncthreads();
    }
    if (tid < NBLK_N) blockoff[tid] = s[tid] - orig;
    if (tid == 0) {
        int off = 0;
        for (int d = DEGBINS - 1; d >= 0; d--) { lo[d] = off; off += lb[d]; }
    }
    __syncthreads();
    if (tid < DEGBINS) degcur[tid] = lo[tid];
}

// 118 blocks x 256: block-local exclusive scan + blockoff -> indptr/cursor;
// degree-sorted permutation via LDS-aggregated counting sort
__global__ void k_apply(const int* __restrict__ counts,
                        const int* __restrict__ blockoff,
                        int* __restrict__ indptr, int* __restrict__ cursor,
                        int* __restrict__ degcur, int* __restrict__ nodeperm) {
    __shared__ int s[256];
    __shared__ int lbins[DEGBINS];
    __shared__ int lbase[DEGBINS];
    const int tid = threadIdx.x;
    const int n = blockIdx.x * 256 + tid;
    const int c = (n < NCROSS) ? counts[n] : 0;
    s[tid] = c;
    if (tid < DEGBINS) lbins[tid] = 0;
    __syncthreads();
    for (int off = 1; off < 256; off <<= 1) {
        int v = (tid >= off) ? s[tid - off] : 0;
        __syncthreads();
        s[tid] += v;
        __syncthreads();
    }
    const int excl = s[tid] - c;
    const int base = blockoff[blockIdx.x];
    int bin = 0, lp = 0;
    if (n < NCROSS) {
        indptr[n] = base + excl;
        cursor[n] = base + excl;
        if (n == NCROSS - 1) indptr[NCROSS] = base + excl + c;
        bin = c < DEGBINS ? c : DEGBINS - 1;
        lp = atomicAdd(&lbins[bin], 1);
    }
    __syncthreads();
    if (tid < DEGBINS) lbase[tid] = lbins[tid] ? atomicAdd(&degcur[tid], lbins[tid]) : 0;
    __syncthreads();
    if (n < NCROSS) nodeperm[lbase[bin] + lp] = n;
}

__global__ void k_scatter(const int* __restrict__ src, const int* __restrict__ dst,
                          int* __restrict__ cursor, int* __restrict__ sorted_src) {
    int i = blockIdx.x * blockDim.x + threadIdx.x;
    if (i < E_EDGES) {
        int p = atomicAdd(&cursor[dst[i]], 1);
        sorted_src[p] = src[i];
    }
}

// ---------------- node features -> h = nodes @ W_gat + b ----------------
// h layout: [tg][n][8 ticks x 4 ch] = 128 B record per (node, tick-group)

__global__ void k_h(const float* __restrict__ x,
                    const int* __restrict__ c0, const int* __restrict__ c1,
                    const int* __restrict__ c2,
                    const int* __restrict__ g01, const int* __restrict__ g12,
                    const int* __restrict__ g20,
                    const float* __restrict__ r01,
                    const float* __restrict__ r12,
                    const float* __restrict__ r20,
                    const float* __restrict__ Wg,
                    const float* __restrict__ bg,
                    float* __restrict__ h) {
    const int n  = blockIdx.x * blockDim.x + threadIdx.x;
    const int tg = blockIdx.y;
    if (n >= NCROSS) return;

    int iA, iB, m;
    float pA, pB;
    const int* cA;
    const int* cB;
    const float* ray;
    if (n < NCPAIR) {
        m = n; cA = c0; cB = c1; pA = 0.f; pB = 1.f; ray = r01;
        iA = g01[2 * m]; iB = g01[2 * m + 1];
    } else if (n < 2 * NCPAIR) {
        m = n - NCPAIR; cA = c1; cB = c2; pA = 1.f; pB = 2.f; ray = r12;
        iA = g12[2 * m]; iB = g12[2 * m + 1];
    } else {
        m = n - 2 * NCPAIR; cA = c2; cB = c0; pA = 2.f; pB = 0.f; ray = r20;
        iA = g20[2 * m]; iB = g20[2 * m + 1];
    }
    const int chA = cA[iA];
    const int chB = cB[iB];
    const float rx = ray[2 * m];
    const float ry = ray[2 * m + 1];

    // tick-static part of nodes @ W_gat + b
    float base[4];
#pragma unroll
    for (int c = 0; c < 4; c++) {
        base[c] = bg[c]
                + (float)iA  * Wg[1 * 4 + c] + (float)chA * Wg[2 * 4 + c]
                + pA         * Wg[4 * 4 + c]
                + (float)iB  * Wg[6 * 4 + c] + (float)chB * Wg[7 * 4 + c]
                + pB         * Wg[9 * 4 + c]
                + rx         * Wg[10 * 4 + c] + ry * Wg[11 * 4 + c];
    }

    const float4 xa0 = *(const float4*)(x + chA * T_TICKS + tg * TG);
    const float4 xa1 = *(const float4*)(x + chA * T_TICKS + tg * TG + 4);
    const float4 xb0 = *(const float4*)(x + chB * T_TICKS + tg * TG);
    const float4 xb1 = *(const float4*)(x + chB * T_TICKS + tg * TG + 4);
    const float sa[8] = {xa0.x, xa0.y, xa0.z, xa0.w, xa1.x, xa1.y, xa1.z, xa1.w};
    const float sb[8] = {xb0.x, xb0.y, xb0.z, xb0.w, xb1.x, xb1.y, xb1.z, xb1.w};

    float4* rec = (float4*)(h + ((size_t)tg * NCROSS + n) * 32);
#pragma unroll
    for (int k = 0; k < TG; k++) {
        const float tk = (float)(tg * TG + k);
        float4 hv;
        hv.x = base[0] + sa[k] * Wg[0] + sb[k] * Wg[5 * 4 + 0] + tk * Wg[12 * 4 + 0];
        hv.y = base[1] + sa[k] * Wg[1] + sb[k] * Wg[5 * 4 + 1] + tk * Wg[12 * 4 + 1];
        hv.z = base[2] + sa[k] * Wg[2] + sb[k] * Wg[5 * 4 + 2] + tk * Wg[12 * 4 + 2];
        hv.w = base[3] + sa[k] * Wg[3] + sb[k] * Wg[5 * 4 + 3] + tk * Wg[12 * 4 + 3];
        rec[k] = hv;
    }
}

// ---------------- GAT aggregation + MLP + sigmoid ----------------
// one thread = (node, tick-group of 8); single-pass online softmax;
// nodes processed in descending-degree order -> uniform loop trips per wave.

__global__ void k_gat(const float* __restrict__ h, const int* __restrict__ indptr,
                      const int* __restrict__ ssrc,
                      const int* __restrict__ nodeperm,
                      const float* __restrict__ as_,
                      const float* __restrict__ ad_,
                      const float* __restrict__ Wm,
                      const float* __restrict__ bm,
                      float* __restrict__ out) {
    // XCD-confined swizzle: tick-group tg runs (heuristically) on XCD tg%8
    const int lid = blockIdx.x;
    const int xcd = lid & 7;
    const int s   = lid >> 3;            // 0 .. 2*NBLK_N-1
    const int half = s / NBLK_N;         // 0 or 1
    const int tg  = xcd + 8 * half;
    const int nb  = s - NBLK_N * half;
    const int idx = nb * 256 + threadIdx.x;
    if (idx >= NCROSS) return;
    const int n = nodeperm[idx];

    const float a0 = as_[0], a1 = as_[1], a2 = as_[2], a3 = as_[3];
    const float d0 = ad_[0], d1 = ad_[1], d2 = ad_[2], d3 = ad_[3];

    const float4* slab = (const float4*)(h + (size_t)tg * NCROSS * 32);

    // dd per tick from own record
    float dd[TG];
    {
        const float4* own = slab + (size_t)n * 8;
#pragma unroll
        for (int k = 0; k < TG; k++) {
            const float4 v = own[k];
            dd[k] = v.x * d0 + v.y * d1 + v.z * d2 + v.w * d3;
        }
    }

    float mx[TG], den[TG];
    float m0[TG], m1[TG], m2[TG], m3[TG];
#pragma unroll
    for (int k = 0; k < TG; k++) {
        mx[k] = -INFINITY; den[k] = 0.f;
        m0[k] = 0.f; m1[k] = 0.f; m2[k] = 0.f; m3[k] = 0.f;
    }

    const int beg = indptr[n];
    const int end = indptr[n + 1];
    int src = (beg < end) ? ssrc[beg] : 0;
    for (int j = beg; j < end; j++) {
        const int cur = src;
        if (j + 1 < end) src = ssrc[j + 1];
        const float4* rec = slab + (size_t)cur * 8;
#pragma unroll
        for (int k = 0; k < TG; k++) {
            const float4 hs = rec[k];
            float e = fmaf(hs.x, a0, fmaf(hs.y, a1, fmaf(hs.z, a2,
                      fmaf(hs.w, a3, dd[k]))));
            e = (e > 0.f) ? e : 0.2f * e;
            const float mn = fmaxf(mx[k], e);
            const float scale = __expf(mx[k] - mn);
            const float w = __expf(e - mn);
            mx[k] = mn;
            den[k] = den[k] * scale + w;
            m0[k] = m0[k] * scale + w * hs.x;
            m1[k] = m1[k] * scale + w * hs.y;
            m2[k] = m2[k] * scale + w * hs.z;
            m3[k] = m3[k] * scale + w * hs.w;
        }
    }

    const float w0 = Wm[0], w1 = Wm[1], w2 = Wm[2], w3 = Wm[3], bb = bm[0];
#pragma unroll
    for (int k = 0; k < TG; k++) {
        const float inv = 1.f / (den[k] + 1e-9f);
        const float logit = (m0[k] * w0 + m1[k] * w1 + m2[k] * w2 + m3[k] * w3)
                            * inv + bb;
        const float o = 1.f / (1.f + __expf(-logit));
        out[(size_t)(tg * TG + k) * NCROSS + n] = o;
    }
}

// ---------------- launch ----------------

extern "C" void kernel_launch(void* const* d_in, const int* in_sizes, int n_in,
                              void* d_out, int out_size, void* d_ws, size_t ws_size,
                              hipStream_t stream) {
    const float* x   = (const float*)d_in[0];
    const int* c0  = (const int*)d_in[1];
    const int* c1  = (const int*)d_in[2];
    const int* c2  = (const int*)d_in[3];
    const int* g01 = (const int*)d_in[4];
    const int* g12 = (const int*)d_in[5];
    const int* g20 = (const int*)d_in[6];
    const float* r01 = (const float*)d_in[7];
    const float* r12 = (const float*)d_in[8];
    const float* r20 = (const float*)d_in[9];
    const int* edges = (const int*)d_in[10];          // [2, E]
    const float* Wg  = (const float*)d_in[11];
    const float* as_ = (const float*)d_in[12];
    const float* ad_ = (const float*)d_in[13];
    const float* bg  = (const float*)d_in[14];
    const float* Wm  = (const float*)d_in[15];
    const float* bm  = (const float*)d_in[16];
    float* out = (float*)d_out;

    const int* e_src = edges;
    const int* e_dst = edges + E_EDGES;

    // workspace layout (counts+degbins contiguous for single memset)
    char* ws = (char*)d_ws;
    size_t off = 0;
    int* counts     = (int*)(ws + off); off += NCROSS * sizeof(int);
    int* degbins    = (int*)(ws + off); off += DEGBINS * sizeof(int);
    int* indptr     = (int*)(ws + off); off += (NCROSS + 1) * sizeof(int);
    int* cursor     = (int*)(ws + off); off += NCROSS * sizeof(int);
    int* sorted_src = (int*)(ws + off); off += E_EDGES * sizeof(int);
    int* blocksum   = (int*)(ws + off); off += 128 * sizeof(int);
    int* blockoff   = (int*)(ws + off); off += 128 * sizeof(int);
    int* degcur     = (int*)(ws + off); off += DEGBINS * sizeof(int);
    int* nodeperm   = (int*)(ws + off); off += NCROSS * sizeof(int);
    off = (off + 255) & ~(size_t)255;
    float* h        = (float*)(ws + off);  // 61,440,000 B
    (void)ws_size; (void)n_in; (void)in_sizes; (void)out_size;

    hipMemsetAsync(counts, 0, (NCROSS + DEGBINS) * sizeof(int), stream);

    const int eb = (E_EDGES + 255) / 256;
    k_hist<<<eb, 256, 0, stream>>>(e_dst, counts);
    k_pre<<<NBLK_N, 256, 0, stream>>>(counts, blocksum, degbins);
    k_top<<<1, 128, 0, stream>>>(blocksum, blockoff, degbins, degcur);
    k_apply<<<NBLK_N, 256, 0, stream>>>(counts, blockoff, indptr, cursor,
                                        degcur, nodeperm);
    k_scatter<<<eb, 256, 0, stream>>>(e_src, e_dst, cursor, sorted_src);

    dim3 gridH(NBLK_N, NTG);
    k_h<<<gridH, 256, 0, stream>>>(x, c0, c1, c2, g01, g12, g20, r01, r12, r20,
                                   Wg, bg, h);
    k_gat<<<NBLK_N * NTG, 256, 0, stream>>>(h, indptr, sorted_src, nodeperm,
                                            as_, ad_, Wm, bm, out);
}

// Round 5
// 208.984 us; speedup vs baseline: 2.0061x; 1.0042x over previous
//
#include <hip/hip_runtime.h>

// Problem constants (match reference)
#define T_TICKS 128
#define NCHAN   1536
#define NCPAIR  10000
#define NCROSS  30000
#define E_EDGES 120000
#define TG      8              // ticks per group
#define NTG     (T_TICKS / TG) // 16 tick groups
#define NBLK_N  ((NCROSS + 255) / 256)  // 118 blocks over nodes
#define DEGBINS 64

// ---------------- CSR build (graph is tick-independent) ----------------

__global__ void k_hist(const int* __restrict__ dst, int* __restrict__ counts) {
    int i = blockIdx.x * blockDim.x + threadIdx.x;
    if (i < E_EDGES) atomicAdd(&counts[dst[i]], 1);
}

// 118 blocks x 256. Per block: local scan of counts, block base via one
// global atomicAdd (CSR bucket order is irrelevant), block-LOCAL descending
// degree counting-sort -> packed (beg,deg,node) records. Keeping the
// permutation inside each 256-node window preserves out-write coalescing.
__global__ void k_apply(const int* __restrict__ counts, int* __restrict__ gbase,
                        int* __restrict__ cursor, int4* __restrict__ begdegn) {
    __shared__ int s[256];
    __shared__ int bins[DEGBINS];
    __shared__ int binoff[DEGBINS];
    __shared__ int sbase;
    const int tid = threadIdx.x;
    const int n = blockIdx.x * 256 + tid;
    const int c = (n < NCROSS) ? counts[n] : 0;
    s[tid] = c;
    if (tid < DEGBINS) bins[tid] = 0;
    __syncthreads();
    for (int off = 1; off < 256; off <<= 1) {
        int v = (tid >= off) ? s[tid - off] : 0;
        __syncthreads();
        s[tid] += v;
        __syncthreads();
    }
    if (tid == 0) sbase = atomicAdd(gbase, s[255]);
    int bin = 0, lp = 0;
    if (n < NCROSS) {
        bin = c < DEGBINS ? c : DEGBINS - 1;
        lp = atomicAdd(&bins[bin], 1);
    }
    __syncthreads();
    if (tid == 0) {
        int run = 0;
        for (int d = DEGBINS - 1; d >= 0; d--) { binoff[d] = run; run += bins[d]; }
    }
    __syncthreads();
    if (n < NCROSS) {
        const int beg = sbase + s[tid] - c;
        cursor[n] = beg;
        const int rank = binoff[bin] + lp;
        begdegn[blockIdx.x * 256 + rank] = make_int4(beg, c, n, 0);
    }
}

__global__ void k_scatter(const int* __restrict__ src, const int* __restrict__ dst,
                          int* __restrict__ cursor, int* __restrict__ sorted_src) {
    int i = blockIdx.x * blockDim.x + threadIdx.x;
    if (i < E_EDGES) {
        int p = atomicAdd(&cursor[dst[i]], 1);
        sorted_src[p] = src[i];
    }
}

// ---------------- node features -> h = nodes @ W_gat + b ----------------
// h layout: [tg][n][8 ticks x 4 ch] = 128 B record per (node, tick-group).
// One thread handles 4 consecutive tick-groups: index gathers amortized 4x,
// x reads become one contiguous 128 B stretch per channel.

__global__ void k_h(const float* __restrict__ x,
                    const int* __restrict__ c0, const int* __restrict__ c1,
                    const int* __restrict__ c2,
                    const int* __restrict__ g01, const int* __restrict__ g12,
                    const int* __restrict__ g20,
                    const float* __restrict__ r01,
                    const float* __restrict__ r12,
                    const float* __restrict__ r20,
                    const float* __restrict__ Wg,
                    const float* __restrict__ bg,
                    float* __restrict__ h) {
    const int n = blockIdx.x * blockDim.x + threadIdx.x;
    if (n >= NCROSS) return;

    int iA, iB, m;
    float pA, pB;
    const int* cA;
    const int* cB;
    const float* ray;
    if (n < NCPAIR) {
        m = n; cA = c0; cB = c1; pA = 0.f; pB = 1.f; ray = r01;
        iA = g01[2 * m]; iB = g01[2 * m + 1];
    } else if (n < 2 * NCPAIR) {
        m = n - NCPAIR; cA = c1; cB = c2; pA = 1.f; pB = 2.f; ray = r12;
        iA = g12[2 * m]; iB = g12[2 * m + 1];
    } else {
        m = n - 2 * NCPAIR; cA = c2; cB = c0; pA = 2.f; pB = 0.f; ray = r20;
        iA = g20[2 * m]; iB = g20[2 * m + 1];
    }
    const int chA = cA[iA];
    const int chB = cB[iB];
    const float rx = ray[2 * m];
    const float ry = ray[2 * m + 1];

    // tick-static part of nodes @ W_gat + b
    float base[4];
#pragma unroll
    for (int c = 0; c < 4; c++) {
        base[c] = bg[c]
                + (float)iA  * Wg[1 * 4 + c] + (float)chA * Wg[2 * 4 + c]
                + pA         * Wg[4 * 4 + c]
                + (float)iB  * Wg[6 * 4 + c] + (float)chB * Wg[7 * 4 + c]
                + pB         * Wg[9 * 4 + c]
                + rx         * Wg[10 * 4 + c] + ry * Wg[11 * 4 + c];
    }

#pragma unroll
    for (int tgi = 0; tgi < 4; tgi++) {
        const int tg = blockIdx.y * 4 + tgi;
        const float4 xa0 = *(const float4*)(x + chA * T_TICKS + tg * TG);
        const float4 xa1 = *(const float4*)(x + chA * T_TICKS + tg * TG + 4);
        const float4 xb0 = *(const float4*)(x + chB * T_TICKS + tg * TG);
        const float4 xb1 = *(const float4*)(x + chB * T_TICKS + tg * TG + 4);
        const float sa[8] = {xa0.x, xa0.y, xa0.z, xa0.w, xa1.x, xa1.y, xa1.z, xa1.w};
        const float sb[8] = {xb0.x, xb0.y, xb0.z, xb0.w, xb1.x, xb1.y, xb1.z, xb1.w};

        float4* rec = (float4*)(h + ((size_t)tg * NCROSS + n) * 32);
#pragma unroll
        for (int k = 0; k < TG; k++) {
            const float tk = (float)(tg * TG + k);
            float4 hv;
            hv.x = base[0] + sa[k] * Wg[0] + sb[k] * Wg[5*4+0] + tk * Wg[12*4+0];
            hv.y = base[1] + sa[k] * Wg[1] + sb[k] * Wg[5*4+1] + tk * Wg[12*4+1];
            hv.z = base[2] + sa[k] * Wg[2] + sb[k] * Wg[5*4+2] + tk * Wg[12*4+2];
            hv.w = base[3] + sa[k] * Wg[3] + sb[k] * Wg[5*4+3] + tk * Wg[12*4+3];
            rec[k] = hv;
        }
    }
}

// ---------------- GAT aggregation + MLP + sigmoid ----------------
// one thread = (node, tick-group of 8); single-pass online softmax with
// single-exp update; MLP folded into scalar accumulator p = sum w*(h.Wm);
// edges processed in pairs for memory-level parallelism.

__device__ __forceinline__ void upd(float& mx, float& den, float& p,
                                    const float e, const float pj) {
    const float dif = e - mx;
    const float ex = __expf(-fabsf(dif));
    const bool g = dif > 0.f;
    const float scale = g ? ex : 1.f;
    const float w = g ? 1.f : ex;
    mx = g ? e : mx;
    den = fmaf(den, scale, w);
    p = fmaf(p, scale, w * pj);
}

__global__ void k_gat(const float* __restrict__ h,
                      const int4* __restrict__ begdegn,
                      const int* __restrict__ ssrc,
                      const float* __restrict__ as_,
                      const float* __restrict__ ad_,
                      const float* __restrict__ Wm,
                      const float* __restrict__ bm,
                      float* __restrict__ out) {
    // XCD-confined swizzle: tick-group tg runs (heuristically) on XCD tg%8
    const int lid = blockIdx.x;
    const int xcd = lid & 7;
    const int s   = lid >> 3;            // 0 .. 2*NBLK_N-1
    const int half = s / NBLK_N;         // 0 or 1
    const int tg  = xcd + 8 * half;
    const int nb  = s - NBLK_N * half;
    const int idx = nb * 256 + threadIdx.x;
    if (idx >= NCROSS) return;
    const int4 bd = begdegn[idx];
    const int beg = bd.x, deg = bd.y, n = bd.z;

    const float a0 = as_[0], a1 = as_[1], a2 = as_[2], a3 = as_[3];
    const float d0 = ad_[0], d1 = ad_[1], d2 = ad_[2], d3 = ad_[3];
    const float w0 = Wm[0], w1 = Wm[1], w2 = Wm[2], w3 = Wm[3], bb = bm[0];

    const float4* slab = (const float4*)(h + (size_t)tg * NCROSS * 32);

    // dd per tick from own record
    float dd[TG];
    {
        const float4* own = slab + (size_t)n * 8;
#pragma unroll
        for (int k = 0; k < TG; k++) {
            const float4 v = own[k];
            dd[k] = v.x * d0 + v.y * d1 + v.z * d2 + v.w * d3;
        }
    }

    float mx[TG], den[TG], p[TG];
#pragma unroll
    for (int k = 0; k < TG; k++) { mx[k] = -INFINITY; den[k] = 0.f; p[k] = 0.f; }

    int j = beg;
    const int e2 = beg + (deg & ~1);
    for (; j < e2; j += 2) {
        const int s0 = ssrc[j];
        const int s1 = ssrc[j + 1];
        const float4* r0 = slab + (size_t)s0 * 8;
        const float4* r1 = slab + (size_t)s1 * 8;
#pragma unroll
        for (int k = 0; k < TG; k++) {
            const float4 h0 = r0[k];
            const float4 h1 = r1[k];
            float ea = fmaf(h0.x, a0, fmaf(h0.y, a1, fmaf(h0.z, a2,
                       fmaf(h0.w, a3, dd[k]))));
            ea = fmaxf(ea, 0.2f * ea);
            const float pa = fmaf(h0.x, w0, fmaf(h0.y, w1, fmaf(h0.z, w2,
                             h0.w * w3)));
            upd(mx[k], den[k], p[k], ea, pa);
            float eb = fmaf(h1.x, a0, fmaf(h1.y, a1, fmaf(h1.z, a2,
                       fmaf(h1.w, a3, dd[k]))));
            eb = fmaxf(eb, 0.2f * eb);
            const float pb = fmaf(h1.x, w0, fmaf(h1.y, w1, fmaf(h1.z, w2,
                             h1.w * w3)));
            upd(mx[k], den[k], p[k], eb, pb);
        }
    }
    if (deg & 1) {
        const float4* r0 = slab + (size_t)ssrc[j] * 8;
#pragma unroll
        for (int k = 0; k < TG; k++) {
            const float4 h0 = r0[k];
            float ea = fmaf(h0.x, a0, fmaf(h0.y, a1, fmaf(h0.z, a2,
                       fmaf(h0.w, a3, dd[k]))));
            ea = fmaxf(ea, 0.2f * ea);
            const float pa = fmaf(h0.x, w0, fmaf(h0.y, w1, fmaf(h0.z, w2,
                             h0.w * w3)));
            upd(mx[k], den[k], p[k], ea, pa);
        }
    }

#pragma unroll
    for (int k = 0; k < TG; k++) {
        const float logit = p[k] / (den[k] + 1e-9f) + bb;
        const float o = 1.f / (1.f + __expf(-logit));
        out[(size_t)(tg * TG + k) * NCROSS + n] = o;
    }
}

// ---------------- launch ----------------

extern "C" void kernel_launch(void* const* d_in, const int* in_sizes, int n_in,
                              void* d_out, int out_size, void* d_ws, size_t ws_size,
                              hipStream_t stream) {
    const float* x   = (const float*)d_in[0];
    const int* c0  = (const int*)d_in[1];
    const int* c1  = (const int*)d_in[2];
    const int* c2  = (const int*)d_in[3];
    const int* g01 = (const int*)d_in[4];
    const int* g12 = (const int*)d_in[5];
    const int* g20 = (const int*)d_in[6];
    const float* r01 = (const float*)d_in[7];
    const float* r12 = (const float*)d_in[8];
    const float* r20 = (const float*)d_in[9];
    const int* edges = (const int*)d_in[10];          // [2, E]
    const float* Wg  = (const float*)d_in[11];
    const float* as_ = (const float*)d_in[12];
    const float* ad_ = (const float*)d_in[13];
    const float* bg  = (const float*)d_in[14];
    const float* Wm  = (const float*)d_in[15];
    const float* bm  = (const float*)d_in[16];
    float* out = (float*)d_out;

    const int* e_src = edges;
    const int* e_dst = edges + E_EDGES;

    // workspace layout (counts+gbase contiguous for single memset)
    char* ws = (char*)d_ws;
    size_t off = 0;
    int* counts     = (int*)(ws + off); off += NCROSS * sizeof(int);
    int* gbase      = (int*)(ws + off); off += sizeof(int);
    int* cursor     = (int*)(ws + off); off += NCROSS * sizeof(int);
    int* sorted_src = (int*)(ws + off); off += E_EDGES * sizeof(int);
    off = (off + 15) & ~(size_t)15;
    int4* begdegn   = (int4*)(ws + off); off += (size_t)NBLK_N * 256 * sizeof(int4);
    off = (off + 255) & ~(size_t)255;
    float* h        = (float*)(ws + off);  // 61,440,000 B
    (void)ws_size; (void)n_in; (void)in_sizes; (void)out_size;

    hipMemsetAsync(counts, 0, (NCROSS + 1) * sizeof(int), stream);

    const int eb = (E_EDGES + 255) / 256;
    k_hist<<<eb, 256, 0, stream>>>(e_dst, counts);
    k_apply<<<NBLK_N, 256, 0, stream>>>(counts, gbase, cursor, begdegn);
    k_scatter<<<eb, 256, 0, stream>>>(e_src, e_dst, cursor, sorted_src);

    dim3 gridH(NBLK_N, 4);
    k_h<<<gridH, 256, 0, stream>>>(x, c0, c1, c2, g01, g12, g20, r01, r12, r20,
                                   Wg, bg, h);
    k_gat<<<NBLK_N * NTG, 256, 0, stream>>>(h, begdegn, sorted_src,
                                            as_, ad_, Wm, bm, out);
}

// Round 6
// 153.041 us; speedup vs baseline: 2.7394x; 1.3655x over previous
//
#include <hip/hip_runtime.h>

// Problem constants (match reference)
#define T_TICKS 128
#define NCHAN   1536
#define NCPAIR  10000
#define NCROSS  30000
#define E_EDGES 120000
#define TG      4              // ticks per group in k_gat
#define NTG     (T_TICKS / TG) // 32 tick groups
#define NBLK_N  ((NCROSS + 255) / 256)  // 118 blocks over nodes
#define DEGBINS 64
#define EPB     ((E_EDGES + NBLK_N - 1) / NBLK_N)  // 1017 edges per hist block

// ---------------- CSR build (graph is tick-independent) ----------------

// 118 blocks x 256. Per block: local scan of counts, block base via one
// global atomicAdd (CSR bucket order is irrelevant), block-LOCAL descending
// degree counting-sort -> packed (beg,deg,node) records. Keeping the
// permutation inside each 256-node window lets k_gat un-permute via LDS.
__global__ void k_apply(const int* __restrict__ counts, int* __restrict__ gbase,
                        int* __restrict__ cursor, int4* __restrict__ begdegn) {
    __shared__ int s[256];
    __shared__ int bins[DEGBINS];
    __shared__ int binoff[DEGBINS];
    __shared__ int sbase;
    const int tid = threadIdx.x;
    const int n = blockIdx.x * 256 + tid;
    const int c = (n < NCROSS) ? counts[n] : 0;
    s[tid] = c;
    if (tid < DEGBINS) bins[tid] = 0;
    __syncthreads();
    for (int off = 1; off < 256; off <<= 1) {
        int v = (tid >= off) ? s[tid - off] : 0;
        __syncthreads();
        s[tid] += v;
        __syncthreads();
    }
    if (tid == 0) sbase = atomicAdd(gbase, s[255]);
    int bin = 0, lp = 0;
    if (n < NCROSS) {
        bin = c < DEGBINS ? c : DEGBINS - 1;
        lp = atomicAdd(&bins[bin], 1);
    }
    __syncthreads();
    if (tid == 0) {
        int run = 0;
        for (int d = DEGBINS - 1; d >= 0; d--) { binoff[d] = run; run += bins[d]; }
    }
    __syncthreads();
    if (n < NCROSS) {
        const int beg = sbase + s[tid] - c;
        cursor[n] = beg;
        const int rank = binoff[bin] + lp;
        begdegn[blockIdx.x * 256 + rank] = make_int4(beg, c, n, 0);
    }
}

__global__ void k_scatter(const int* __restrict__ src, const int* __restrict__ dst,
                          int* __restrict__ cursor, int* __restrict__ sorted_src) {
    int i = blockIdx.x * blockDim.x + threadIdx.x;
    if (i < E_EDGES) {
        int p = atomicAdd(&cursor[dst[i]], 1);
        sorted_src[p] = src[i];
    }
}

// ---------------- per-(node,tick) scalar features s,d,p ----------------
// s = h.a_src, d = h.a_dst, p = h.Wm where h = nodes @ W_gat + b_gat.
// sp layout: [tg4][n][4 ticks x (s,p)] = 32 B; dv layout: [tg4][n][4] = 16 B.
// Edge histogram fused into blockIdx.y==0 blocks (saves a dispatch).

__global__ void k_feat(const float* __restrict__ x,
                       const int* __restrict__ c0, const int* __restrict__ c1,
                       const int* __restrict__ c2,
                       const int* __restrict__ g01, const int* __restrict__ g12,
                       const int* __restrict__ g20,
                       const float* __restrict__ r01,
                       const float* __restrict__ r12,
                       const float* __restrict__ r20,
                       const float* __restrict__ Wg,
                       const float* __restrict__ bg,
                       const float* __restrict__ as_,
                       const float* __restrict__ ad_,
                       const float* __restrict__ Wm,
                       const int* __restrict__ e_dst, int* __restrict__ counts,
                       float4* __restrict__ sp4, float4* __restrict__ dv4) {
    const int tid = threadIdx.x;
    const int tg8 = blockIdx.y;
    // fused edge histogram
    if (tg8 == 0) {
        const int lo = blockIdx.x * EPB;
        const int hi = min(lo + EPB, E_EDGES);
        for (int i = lo + tid; i < hi; i += 256) atomicAdd(&counts[e_dst[i]], 1);
    }
    const int n = blockIdx.x * 256 + tid;
    if (n >= NCROSS) return;

    int iA, iB, m;
    float pA, pB;
    const int* cA;
    const int* cB;
    const float* ray;
    if (n < NCPAIR) {
        m = n; cA = c0; cB = c1; pA = 0.f; pB = 1.f; ray = r01;
        iA = g01[2 * m]; iB = g01[2 * m + 1];
    } else if (n < 2 * NCPAIR) {
        m = n - NCPAIR; cA = c1; cB = c2; pA = 1.f; pB = 2.f; ray = r12;
        iA = g12[2 * m]; iB = g12[2 * m + 1];
    } else {
        m = n - 2 * NCPAIR; cA = c2; cB = c0; pA = 2.f; pB = 0.f; ray = r20;
        iA = g20[2 * m]; iB = g20[2 * m + 1];
    }
    const int chA = cA[iA];
    const int chB = cB[iB];
    const float rx = ray[2 * m];
    const float ry = ray[2 * m + 1];

    // tick-static part of nodes @ W_gat + b
    float base[4];
#pragma unroll
    for (int c = 0; c < 4; c++) {
        base[c] = bg[c]
                + (float)iA  * Wg[1 * 4 + c] + (float)chA * Wg[2 * 4 + c]
                + pA         * Wg[4 * 4 + c]
                + (float)iB  * Wg[6 * 4 + c] + (float)chB * Wg[7 * 4 + c]
                + pB         * Wg[9 * 4 + c]
                + rx         * Wg[10 * 4 + c] + ry * Wg[11 * 4 + c];
    }
    // project everything onto the three output directions
    float sB = 0, dB = 0, pBs = 0;          // base projections
    float sA1 = 0, dA1 = 0, pA1 = 0;        // coeff of sigA
    float sB1 = 0, dB1 = 0, pB1 = 0;        // coeff of sigB
    float sT = 0, dT = 0, pT = 0;           // coeff of tick
#pragma unroll
    for (int c = 0; c < 4; c++) {
        const float va = as_[c], vd = ad_[c], vm = Wm[c];
        sB  += base[c] * va;  dB  += base[c] * vd;  pBs += base[c] * vm;
        sA1 += Wg[c] * va;    dA1 += Wg[c] * vd;    pA1 += Wg[c] * vm;
        sB1 += Wg[5*4+c]*va;  dB1 += Wg[5*4+c]*vd;  pB1 += Wg[5*4+c]*vm;
        sT  += Wg[12*4+c]*va; dT  += Wg[12*4+c]*vd; pT  += Wg[12*4+c]*vm;
    }

#pragma unroll
    for (int half = 0; half < 2; half++) {
        const int tg4 = tg8 * 2 + half;
        const float4 xa = *(const float4*)(x + chA * T_TICKS + tg4 * TG);
        const float4 xb = *(const float4*)(x + chB * T_TICKS + tg4 * TG);
        const float sa[4] = {xa.x, xa.y, xa.z, xa.w};
        const float sb[4] = {xb.x, xb.y, xb.z, xb.w};
        float sv[4], dvv[4], pv[4];
#pragma unroll
        for (int k = 0; k < TG; k++) {
            const float tk = (float)(tg4 * TG + k);
            sv[k]  = sB  + sa[k]*sA1 + sb[k]*sB1 + tk*sT;
            dvv[k] = dB  + sa[k]*dA1 + sb[k]*dB1 + tk*dT;
            pv[k]  = pBs + sa[k]*pA1 + sb[k]*pB1 + tk*pT;
        }
        const size_t rec = (size_t)tg4 * NCROSS + n;
        sp4[rec * 2]     = make_float4(sv[0], pv[0], sv[1], pv[1]);
        sp4[rec * 2 + 1] = make_float4(sv[2], pv[2], sv[3], pv[3]);
        dv4[rec]         = make_float4(dvv[0], dvv[1], dvv[2], dvv[3]);
    }
}

// ---------------- GAT aggregation + MLP + sigmoid ----------------
// one thread = (node, 4 ticks); single-pass online softmax (single exp);
// reads only precomputed (s,p) pairs: 32 B per edge-visit.
// Epilogue un-permutes through LDS so out-stores are tid-coalesced.

__device__ __forceinline__ void upd(float& mx, float& den, float& p,
                                    const float e, const float pj) {
    const float dif = e - mx;
    const float ex = __expf(-fabsf(dif));
    const bool g = dif > 0.f;
    const float scale = g ? ex : 1.f;
    const float w = g ? 1.f : ex;
    mx = g ? e : mx;
    den = fmaf(den, scale, w);
    p = fmaf(p, scale, w * pj);
}

__device__ __forceinline__ void edge_upd(const float4 f0, const float4 f1,
                                         const float* dd, float* mx,
                                         float* den, float* pa) {
    float e0 = f0.x + dd[0]; e0 = fmaxf(e0, 0.2f * e0);
    upd(mx[0], den[0], pa[0], e0, f0.y);
    float e1 = f0.z + dd[1]; e1 = fmaxf(e1, 0.2f * e1);
    upd(mx[1], den[1], pa[1], e1, f0.w);
    float e2 = f1.x + dd[2]; e2 = fmaxf(e2, 0.2f * e2);
    upd(mx[2], den[2], pa[2], e2, f1.y);
    float e3 = f1.z + dd[3]; e3 = fmaxf(e3, 0.2f * e3);
    upd(mx[3], den[3], pa[3], e3, f1.w);
}

__global__ void k_gat(const float4* __restrict__ sp4,
                      const float4* __restrict__ dv4,
                      const int4* __restrict__ begdegn,
                      const int* __restrict__ ssrc,
                      const float* __restrict__ bm,
                      float* __restrict__ out) {
    // XCD-confined swizzle: 8 consecutive blocks = same node window, 8 tgs
    // on (heuristically) 8 XCDs; q advances over time so each XCD holds
    // ~one 0.96 MB sp-slab + 0.48 MB dv-slab live in its L2.
    const int lid = blockIdx.x;
    const int xcd = lid & 7;
    const int s   = lid >> 3;            // 0 .. 4*NBLK_N-1
    const int q   = s / NBLK_N;          // 0..3
    const int nb  = s - q * NBLK_N;
    const int tg  = xcd + 8 * q;
    const int bbase = nb * 256;
    const int tid = threadIdx.x;
    const int idx = bbase + tid;

    __shared__ float lres[TG][257];

    if (idx < NCROSS) {
        const int4 bd = begdegn[idx];
        const int beg = bd.x, deg = bd.y, n = bd.z;
        const int localn = n & 255;
        const float bb = bm[0];

        const float4* spb = sp4 + (size_t)tg * NCROSS * 2;
        const float4 dvv = dv4[(size_t)tg * NCROSS + n];
        const float dd[TG] = {dvv.x, dvv.y, dvv.z, dvv.w};

        float mx[TG], den[TG], pa[TG];
#pragma unroll
        for (int k = 0; k < TG; k++) { mx[k] = -INFINITY; den[k] = 0.f; pa[k] = 0.f; }

        int j = beg;
        const int e2 = beg + (deg & ~1);
        for (; j < e2; j += 2) {
            const int s0 = ssrc[j];
            const int s1 = ssrc[j + 1];
            const float4 f0 = spb[(size_t)s0 * 2];
            const float4 f1 = spb[(size_t)s0 * 2 + 1];
            const float4 f2 = spb[(size_t)s1 * 2];
            const float4 f3 = spb[(size_t)s1 * 2 + 1];
            edge_upd(f0, f1, dd, mx, den, pa);
            edge_upd(f2, f3, dd, mx, den, pa);
        }
        if (deg & 1) {
            const int s0 = ssrc[j];
            const float4 f0 = spb[(size_t)s0 * 2];
            const float4 f1 = spb[(size_t)s0 * 2 + 1];
            edge_upd(f0, f1, dd, mx, den, pa);
        }

#pragma unroll
        for (int k = 0; k < TG; k++) {
            const float logit = pa[k] / (den[k] + 1e-9f) + bb;
            lres[k][localn] = 1.f / (1.f + __expf(-logit));
        }
    }
    __syncthreads();
    if (idx < NCROSS) {
#pragma unroll
        for (int k = 0; k < TG; k++) {
            out[(size_t)(tg * TG + k) * NCROSS + bbase + tid] = lres[k][tid];
        }
    }
}

// ---------------- launch ----------------

extern "C" void kernel_launch(void* const* d_in, const int* in_sizes, int n_in,
                              void* d_out, int out_size, void* d_ws, size_t ws_size,
                              hipStream_t stream) {
    const float* x   = (const float*)d_in[0];
    const int* c0  = (const int*)d_in[1];
    const int* c1  = (const int*)d_in[2];
    const int* c2  = (const int*)d_in[3];
    const int* g01 = (const int*)d_in[4];
    const int* g12 = (const int*)d_in[5];
    const int* g20 = (const int*)d_in[6];
    const float* r01 = (const float*)d_in[7];
    const float* r12 = (const float*)d_in[8];
    const float* r20 = (const float*)d_in[9];
    const int* edges = (const int*)d_in[10];          // [2, E]
    const float* Wg  = (const float*)d_in[11];
    const float* as_ = (const float*)d_in[12];
    const float* ad_ = (const float*)d_in[13];
    const float* bg  = (const float*)d_in[14];
    const float* Wm  = (const float*)d_in[15];
    const float* bm  = (const float*)d_in[16];
    float* out = (float*)d_out;

    const int* e_src = edges;
    const int* e_dst = edges + E_EDGES;

    // workspace layout (counts+gbase contiguous for single memset)
    char* ws = (char*)d_ws;
    size_t off = 0;
    int* counts     = (int*)(ws + off); off += NCROSS * sizeof(int);
    int* gbase      = (int*)(ws + off); off += sizeof(int);
    int* cursor     = (int*)(ws + off); off += NCROSS * sizeof(int);
    int* sorted_src = (int*)(ws + off); off += E_EDGES * sizeof(int);
    off = (off + 15) & ~(size_t)15;
    int4* begdegn   = (int4*)(ws + off); off += (size_t)NBLK_N * 256 * sizeof(int4);
    off = (off + 255) & ~(size_t)255;
    float4* sp4     = (float4*)(ws + off); off += (size_t)NTG * NCROSS * 32; // 30.7 MB
    float4* dv4     = (float4*)(ws + off); off += (size_t)NTG * NCROSS * 16; // 15.4 MB
    (void)ws_size; (void)n_in; (void)in_sizes; (void)out_size;

    hipMemsetAsync(counts, 0, (NCROSS + 1) * sizeof(int), stream);

    dim3 gridF(NBLK_N, 16);
    k_feat<<<gridF, 256, 0, stream>>>(x, c0, c1, c2, g01, g12, g20,
                                      r01, r12, r20, Wg, bg, as_, ad_, Wm,
                                      e_dst, counts, sp4, dv4);
    k_apply<<<NBLK_N, 256, 0, stream>>>(counts, gbase, cursor, begdegn);
    const int eb = (E_EDGES + 255) / 256;
    k_scatter<<<eb, 256, 0, stream>>>(e_src, e_dst, cursor, sorted_src);
    k_gat<<<NBLK_N * NTG, 256, 0, stream>>>(sp4, dv4, begdegn, sorted_src,
                                            bm, out);
}